// Round 1
// baseline (1226.219 us; speedup 1.0000x reference)
//
#include <hip/hip_runtime.h>
#include <cstddef>

#define PI2F 6.283185307179586f

// ============================ GEMM (M=16384, N=512, K=512) ============================
// TOUT=true: write output in transposed layout T[b][h][e][t]  (col c -> e=c>>3, h=c&7)
// TOUT=false: plain row-major output
template<bool TOUT>
__global__ __launch_bounds__(256)
void gemm_bias_k(const float* __restrict__ X, const float* __restrict__ W,
                 const float* __restrict__ bias, float* __restrict__ out)
{
    __shared__ float As[16][68];
    __shared__ float Bs[16][68];
    __shared__ float Cs[64][68];
    const int tid = threadIdx.x;
    const int i = tid >> 4, j = tid & 15;
    const int m0 = blockIdx.x << 6, n0 = blockIdx.y << 6;
    const int lm = tid >> 2, lkq = tid & 3;
    const int lkk = tid >> 4, lnq = tid & 15;
    const float* Xp = X + (size_t)(m0 + lm) * 512 + lkq * 4;
    const float* Wp = W + (size_t)lkk * 512 + n0 + lnq * 4;
    float c[4][4] = {};
    for (int k0 = 0; k0 < 512; k0 += 16) {
        float4 a4 = *(const float4*)(Xp + k0);
        float4 b4 = *(const float4*)(Wp + (size_t)k0 * 512);
        As[lkq*4+0][lm] = a4.x;
        As[lkq*4+1][lm] = a4.y;
        As[lkq*4+2][lm] = a4.z;
        As[lkq*4+3][lm] = a4.w;
        *(float4*)&Bs[lkk][lnq*4] = b4;
        __syncthreads();
#pragma unroll
        for (int kk = 0; kk < 16; ++kk) {
            float4 av = *(const float4*)&As[kk][i*4];
            float4 bv = *(const float4*)&Bs[kk][j*4];
            float a[4] = {av.x, av.y, av.z, av.w};
            float b[4] = {bv.x, bv.y, bv.z, bv.w};
#pragma unroll
            for (int ii = 0; ii < 4; ++ii)
#pragma unroll
                for (int jj = 0; jj < 4; ++jj)
                    c[ii][jj] = fmaf(a[ii], b[jj], c[ii][jj]);
        }
        __syncthreads();
    }
    if constexpr (TOUT) {
        float bv[4];
#pragma unroll
        for (int r = 0; r < 4; ++r) bv[r] = bias[n0 + j*4 + r];
#pragma unroll
        for (int ii = 0; ii < 4; ++ii)
#pragma unroll
            for (int jj = 0; jj < 4; ++jj)
                Cs[j*4+jj][i*4+ii] = c[ii][jj] + bv[jj];
        __syncthreads();
        const int b_ = m0 >> 10, t0 = m0 & 1023;
        const int col = tid >> 2, seg = tid & 3;
        const int gc = n0 + col;
        const int h = gc & 7, e = gc >> 3;
        float* dst = out + (((size_t)(b_*8 + h) * 64 + e) << 10) + t0;
#pragma unroll
        for (int it = 0; it < 4; ++it) {
            int tl = (it*4 + seg) * 4;
            *(float4*)(dst + tl) = *(float4*)&Cs[col][tl];
        }
    } else {
#pragma unroll
        for (int ii = 0; ii < 4; ++ii) {
            float4 v;
            v.x = c[ii][0] + bias[n0 + j*4 + 0];
            v.y = c[ii][1] + bias[n0 + j*4 + 1];
            v.z = c[ii][2] + bias[n0 + j*4 + 2];
            v.w = c[ii][3] + bias[n0 + j*4 + 3];
            *(float4*)(out + (size_t)(m0 + i*4 + ii) * 512 + n0 + j*4) = v;
        }
    }
}

// ============================ Wavelet transform (T layout) ============================
// in: (b,8,64,2L) -> d,s: (b,8,64,L).  d uses ecd, s uses ecs.
__global__ __launch_bounds__(256)
void wavelet_k(const float* __restrict__ qin, const float* __restrict__ kin,
               float* __restrict__ dq, float* __restrict__ qs,
               float* __restrict__ dk, float* __restrict__ ks,
               const float* __restrict__ ecd, const float* __restrict__ ecs, int L)
{
    __shared__ float sd[16][8];
    __shared__ float ss[16][8];
    if (threadIdx.x < 128) sd[threadIdx.x >> 3][threadIdx.x & 7] = ecd[threadIdx.x];
    else { int u = threadIdx.x - 128; ss[u >> 3][u & 7] = ecs[u]; }
    __syncthreads();
    size_t idx = (size_t)blockIdx.x * 256 + threadIdx.x;
    size_t per = (size_t)1024 * L;     // 16*64*L
    if (idx >= 2 * per) return;
    int tensor = (int)(idx / per);
    size_t r = idx % per;
    int t = (int)(r % L);
    int e = (int)((r / L) & 63);
    int b = (int)(r / ((size_t)L * 64));
    const float* in = tensor ? kin : qin;
    float* od = tensor ? dk : dq;
    float* os = tensor ? ks : qs;
    float xa[16];
#pragma unroll
    for (int h = 0; h < 8; ++h) {
        float2 v = *(const float2*)(in + ((size_t)(b*8 + h) * 64 + e) * (size_t)(2*L) + 2*t);
        xa[h] = v.x; xa[8+h] = v.y;
    }
#pragma unroll
    for (int jj = 0; jj < 8; ++jj) {
        float ad = 0.f, as_ = 0.f;
#pragma unroll
        for (int rr = 0; rr < 16; ++rr) {
            ad  = fmaf(xa[rr], sd[rr][jj], ad);
            as_ = fmaf(xa[rr], ss[rr][jj], as_);
        }
        size_t p = ((size_t)(b*8 + jj) * 64 + e) * L + t;
        od[p] = ad;
        os[p] = as_;
    }
}

// ============================ rfft modes (first M modes) ============================
// one wave per row (row = (b*8+h)*64+e, 8192 rows per tensor); 4 tensors per launch
template<int M>
__global__ __launch_bounds__(256)
void fft_k(const float* __restrict__ in0, const float* __restrict__ in1,
           const float* __restrict__ in2, const float* __restrict__ in3,
           float2* __restrict__ o0, float2* __restrict__ o1,
           float2* __restrict__ o2, float2* __restrict__ o3, int L)
{
    int wave = blockIdx.x * 4 + (threadIdx.x >> 6);
    int lane = threadIdx.x & 63;
    int tensor = wave >> 13;
    int row = wave & 8191;
    const float* in = tensor == 0 ? in0 : tensor == 1 ? in1 : tensor == 2 ? in2 : in3;
    float2* out = tensor == 0 ? o0 : tensor == 1 ? o1 : tensor == 2 ? o2 : o3;
    const float* src = in + (size_t)row * L;
    float re[M], im[M];
#pragma unroll
    for (int jj = 0; jj < M; ++jj) { re[jj] = 0.f; im[jj] = 0.f; }
    const float w = PI2F / (float)L;
    for (int t = lane; t < L; t += 64) {
        float x = src[t];
        re[0] += x;
        if (M > 1) {
            float s1, c1;
            __sincosf(w * (float)t, &s1, &c1);
            float cj = c1, sj = s1;
#pragma unroll
            for (int jj = 1; jj < M; ++jj) {
                re[jj] = fmaf(x, cj, re[jj]);
                im[jj] = fmaf(-x, sj, im[jj]);
                float cn = cj*c1 - sj*s1;
                sj = fmaf(sj, c1, cj*s1);
                cj = cn;
            }
        }
    }
#pragma unroll
    for (int jj = 0; jj < M; ++jj) {
        float r = re[jj], q2 = im[jj];
        for (int off = 32; off > 0; off >>= 1) {
            r  += __shfl_xor(r, off, 64);
            q2 += __shfl_xor(q2, off, 64);
        }
        if (lane == 0) out[(size_t)row * M + jj] = make_float2(r, q2);
    }
}

// ============================ S = QF^T KF, ctanh, U = T * KF ============================
// one block (64 threads) per (path, b, h); path 0: d, path 1: s
template<int M>
__global__ __launch_bounds__(64)
void combine_k(const float2* __restrict__ QFd, const float2* __restrict__ KFd, float2* __restrict__ Md,
               const float2* __restrict__ QFs, const float2* __restrict__ KFs, float2* __restrict__ Ms)
{
    const int path = blockIdx.x >> 7;
    const int bh = blockIdx.x & 127;
    const float2* QF = (path ? QFs : QFd) + (size_t)bh * 64 * M;
    const float2* KF = (path ? KFs : KFd) + (size_t)bh * 64 * M;
    float2* out = (path ? Ms : Md) + (size_t)bh * 64 * M;
    __shared__ float2 qsh[64][M + 1];
    __shared__ float2 ksh[64][M + 1];
    __shared__ float2 ssh[M][M];
    const int lane = threadIdx.x;
    for (int u = lane; u < 64 * M; u += 64) {
        qsh[u / M][u % M] = QF[u];
        ksh[u / M][u % M] = KF[u];
    }
    __syncthreads();
    for (int idx = lane; idx < M * M; idx += 64) {
        int x = idx / M, y = idx % M;
        float sr = 0.f, si = 0.f;
        for (int e = 0; e < 64; ++e) {
            float2 qq = qsh[e][x], kk = ksh[e][y];
            sr = fmaf(qq.x, kk.x, sr); sr = fmaf(-qq.y, kk.y, sr);
            si = fmaf(qq.x, kk.y, si); si = fmaf(qq.y, kk.x, si);
        }
        // complex tanh: (sinh(2a) + i sin(2b)) / (cosh(2a) + cos(2b)), 2a clamped
        float twoa = fminf(fmaxf(2.f * sr, -30.f), 30.f);
        float e2 = expf(twoa);
        float inv = 1.f / e2;
        float s2b, c2b;
        sincosf(2.f * si, &s2b, &c2b);
        float denom = 0.5f * (e2 + inv) + c2b;
        ssh[x][y] = make_float2(0.5f * (e2 - inv) / denom, s2b / denom);
    }
    __syncthreads();
    const int e = lane;
    for (int x = 0; x < M; ++x) {
        float ur = 0.f, ui = 0.f;
        for (int y = 0; y < M; ++y) {
            float2 tt = ssh[x][y], kk = ksh[e][y];
            ur = fmaf(tt.x, kk.x, ur); ur = fmaf(-tt.y, kk.y, ur);
            ui = fmaf(tt.x, kk.y, ui); ui = fmaf(tt.y, kk.x, ui);
        }
        out[(size_t)e * M + x] = make_float2(ur, ui);
    }
}

// ============================ dual irfft: us = irfft(Md), ud = irfft(Md+Ms) ============================
template<int M>
__global__ __launch_bounds__(256)
void irfft_k(const float2* __restrict__ Mdm, const float2* __restrict__ Msm,
             float* __restrict__ us, float* __restrict__ ud, int L, float scale)
{
    size_t idx = (size_t)blockIdx.x * 256 + threadIdx.x;
    if (idx >= (size_t)8192 * L) return;
    int t = (int)(idx % L);
    size_t row = idx / L;
    const float2* md = Mdm + row * M;
    const float2* ms = Msm + row * M;
    float2 d0 = md[0], s0 = ms[0];
    float accs = d0.x;
    float accd = d0.x + s0.x;
    if (M > 1) {
        float s1, c1;
        __sincosf((PI2F / (float)L) * (float)t, &s1, &c1);
        float cj = c1, sj = s1;
#pragma unroll
        for (int jj = 1; jj < M; ++jj) {
            float2 dm = md[jj], sm = ms[jj];
            accs += 2.f * (dm.x * cj - dm.y * sj);
            accd += 2.f * ((dm.x + sm.x) * cj - (dm.y + sm.y) * sj);
            float cn = cj*c1 - sj*s1;
            sj = fmaf(sj, c1, cj*s1);
            cj = cn;
        }
    }
    us[idx] = accs * scale;
    ud[idx] = accd * scale;
}

// ============================ reconstruction: v=(v+Us | Ud) -> even/odd ============================
__global__ __launch_bounds__(256)
void recon_k(const float* __restrict__ vprev, const float* __restrict__ uss,
             const float* __restrict__ udd, const float* __restrict__ rce,
             const float* __restrict__ rco, float* __restrict__ vout, int L)
{
    __shared__ float se[16][8];
    __shared__ float so[16][8];
    if (threadIdx.x < 128) se[threadIdx.x >> 3][threadIdx.x & 7] = rce[threadIdx.x];
    else { int u = threadIdx.x - 128; so[u >> 3][u & 7] = rco[u]; }
    __syncthreads();
    size_t idx = (size_t)blockIdx.x * 256 + threadIdx.x;
    if (idx >= (size_t)1024 * L) return;
    int t = (int)(idx % L);
    int e = (int)((idx / L) & 63);
    int b = (int)(idx / ((size_t)L * 64));
    float a[16];
#pragma unroll
    for (int h = 0; h < 8; ++h) {
        size_t p = ((size_t)(b*8 + h) * 64 + e) * L + t;
        a[h] = vprev[p] + uss[p];
        a[8+h] = udd[p];
    }
#pragma unroll
    for (int jj = 0; jj < 8; ++jj) {
        float ev = 0.f, od = 0.f;
#pragma unroll
        for (int rr = 0; rr < 16; ++rr) {
            ev = fmaf(a[rr], se[rr][jj], ev);
            od = fmaf(a[rr], so[rr][jj], od);
        }
        *(float2*)(vout + ((size_t)(b*8 + jj) * 64 + e) * (size_t)(2*L) + 2*t) = make_float2(ev, od);
    }
}

// ============================ transpose T[b][h][e][t] -> N[b][t][e*8+h] ============================
__global__ __launch_bounds__(256)
void trans_tn_k(const float* __restrict__ vT, float* __restrict__ vN)
{
    __shared__ float Ls[512][17];
    const int b = blockIdx.x >> 6;
    const int t0 = (blockIdx.x & 63) << 4;
    const int tid = threadIdx.x;
#pragma unroll
    for (int it = 0; it < 8; ++it) {
        int u = it * 256 + tid;
        int row = u >> 2, part = u & 3;
        float4 v = *(const float4*)(vT + ((size_t)b * 512 + row) * 1024 + t0 + part * 4);
        Ls[row][part*4+0] = v.x;
        Ls[row][part*4+1] = v.y;
        Ls[row][part*4+2] = v.z;
        Ls[row][part*4+3] = v.w;
    }
    __syncthreads();
#pragma unroll
    for (int it = 0; it < 8; ++it) {
        int u = it * 256 + tid;
        int cq = u & 127, tt = u >> 7;
        int c = cq * 4;
        float4 v;
        v.x = Ls[(((c+0) & 7) << 6) + ((c+0) >> 3)][tt];
        v.y = Ls[(((c+1) & 7) << 6) + ((c+1) >> 3)][tt];
        v.z = Ls[(((c+2) & 7) << 6) + ((c+2) >> 3)][tt];
        v.w = Ls[(((c+3) & 7) << 6) + ((c+3) >> 3)][tt];
        *(float4*)(vN + ((size_t)b * 1024 + t0 + tt) * 512 + c) = v;
    }
}

// ============================ dispatch helpers ============================
static void launch_fft(int m, const float* a, const float* b, const float* c, const float* d,
                       float2* o0, float2* o1, float2* o2, float2* o3, int L, hipStream_t s)
{
    switch (m) {
      case 16: fft_k<16><<<8192,256,0,s>>>(a,b,c,d,o0,o1,o2,o3,L); break;
      case 8:  fft_k<8> <<<8192,256,0,s>>>(a,b,c,d,o0,o1,o2,o3,L); break;
      case 4:  fft_k<4> <<<8192,256,0,s>>>(a,b,c,d,o0,o1,o2,o3,L); break;
      case 2:  fft_k<2> <<<8192,256,0,s>>>(a,b,c,d,o0,o1,o2,o3,L); break;
      default: fft_k<1> <<<8192,256,0,s>>>(a,b,c,d,o0,o1,o2,o3,L); break;
    }
}

static void launch_combine(int m, const float2* QFd, const float2* KFd, float2* Md,
                           const float2* QFs, const float2* KFs, float2* Ms, hipStream_t s)
{
    switch (m) {
      case 16: combine_k<16><<<256,64,0,s>>>(QFd,KFd,Md,QFs,KFs,Ms); break;
      case 8:  combine_k<8> <<<256,64,0,s>>>(QFd,KFd,Md,QFs,KFs,Ms); break;
      case 4:  combine_k<4> <<<256,64,0,s>>>(QFd,KFd,Md,QFs,KFs,Ms); break;
      case 2:  combine_k<2> <<<256,64,0,s>>>(QFd,KFd,Md,QFs,KFs,Ms); break;
      default: combine_k<1> <<<256,64,0,s>>>(QFd,KFd,Md,QFs,KFs,Ms); break;
    }
}

static void launch_irfft(int m, const float2* Md, const float2* Ms,
                         float* us, float* ud, int L, hipStream_t s)
{
    int blocks = (int)(((size_t)8192 * L + 255) / 256);
    float scale = 1.f / (4096.f * (float)L);
    switch (m) {
      case 16: irfft_k<16><<<blocks,256,0,s>>>(Md,Ms,us,ud,L,scale); break;
      case 8:  irfft_k<8> <<<blocks,256,0,s>>>(Md,Ms,us,ud,L,scale); break;
      case 4:  irfft_k<4> <<<blocks,256,0,s>>>(Md,Ms,us,ud,L,scale); break;
      case 2:  irfft_k<2> <<<blocks,256,0,s>>>(Md,Ms,us,ud,L,scale); break;
      default: irfft_k<1> <<<blocks,256,0,s>>>(Md,Ms,us,ud,L,scale); break;
    }
}

// ============================ driver ============================
extern "C" void kernel_launch(void* const* d_in, const int* in_sizes, int n_in,
                              void* d_out, int out_size, void* d_ws, size_t ws_size,
                              hipStream_t stream)
{
    const float* q    = (const float*)d_in[0];
    const float* k    = (const float*)d_in[1];
    const float* Lq_w = (const float*)d_in[3];
    const float* Lq_b = (const float*)d_in[4];
    const float* Lk_w = (const float*)d_in[5];
    const float* Lk_b = (const float*)d_in[6];
    const float* outw = (const float*)d_in[9];
    const float* outb = (const float*)d_in[10];
    const float* ec_s = (const float*)d_in[11];
    const float* ec_d = (const float*)d_in[12];
    const float* rc_e = (const float*)d_in[13];
    const float* rc_o = (const float*)d_in[14];

    float* ws = (float*)d_ws;
    // workspace layout (floats)
    float*  qA   = ws;                       // 8,388,608  (8192*1024)
    float*  kA   = qA + 8388608;             // 8,388,608
    float*  qB   = kA + 8388608;             // 4,194,304
    float*  kB   = qB + 4194304;             // 4,194,304
    float*  dq   = kB + 4194304;             // 4,194,304
    float*  dk   = dq + 4194304;             // 4,194,304
    float*  US   = dk + 4194304;             // 8,380,416  (8192*1023)
    float*  UD   = US + 8380416;             // 8,380,416
    float2* QFd  = (float2*)(UD + 8380416);  // 131,072 float2 each
    float2* KFd  = QFd + 131072;
    float2* QFs  = KFd + 131072;
    float2* KFs  = QFs + 131072;
    float2* Mdm  = KFs + 131072;
    float2* Msm  = Mdm + 131072;
    float*  zero2 = (float*)(Msm + 131072);  // 16,384 floats (len-2 zero tensor)

    // ---- input projections (v path is dead code: FCA never reads v) ----
    dim3 gg(256, 8);
    gemm_bias_k<true><<<gg, 256, 0, stream>>>(q, Lq_w, Lq_b, qA);
    gemm_bias_k<true><<<gg, 256, 0, stream>>>(k, Lk_w, Lk_b, kA);
    hipMemsetAsync(zero2, 0, 16384 * sizeof(float), stream);

    // ---- decomposition levels 0..8 (level 9 and final FCA are exactly zero: m=0 at L=1) ----
    size_t offs[9];
    { size_t o = 0; for (int l = 0; l < 9; ++l) { offs[l] = o; o += (size_t)8192 * (512 >> l); } }

    float* qcur = qA; float* kcur = kA;
    float* qnxt = qB; float* knxt = kB;
    for (int lvl = 0; lvl < 9; ++lvl) {
        int L = 512 >> lvl;                     // FCA length (= wavelet output length)
        int m = (L / 2 < 16) ? L / 2 : 16;
        size_t thr = (size_t)2048 * L;          // 2 tensors * 16*64*L
        wavelet_k<<<(unsigned)((thr + 255) / 256), 256, 0, stream>>>(
            qcur, kcur, dq, qnxt, dk, knxt, ec_d, ec_s, L);
        launch_fft(m, dq, dk, qnxt, knxt, QFd, KFd, QFs, KFs, L, stream);
        launch_combine(m, QFd, KFd, Mdm, QFs, KFs, Msm, stream);
        launch_irfft(m, Mdm, Msm, US + offs[lvl], UD + offs[lvl], L, stream);
        float* t0 = qcur; qcur = qnxt; qnxt = t0;
        float* t1 = kcur; kcur = knxt; knxt = t1;
    }

    // ---- reconstruction: v starts as zeros(len 2) (levels 9/10 contribute nothing) ----
    float* vp = zero2;
    float* bufs[2] = {qA, kA};   // q/k buffers are dead now
    int pb = 0;
    for (int i = 8; i >= 0; --i) {
        int L = 512 >> i;
        size_t thr = (size_t)1024 * L;
        float* vo = bufs[pb]; pb ^= 1;
        recon_k<<<(unsigned)((thr + 255) / 256), 256, 0, stream>>>(
            vp, US + offs[i], UD + offs[i], rc_e, rc_o, vo, L);
        vp = vo;
    }
    // vp == qA, length 1024, T layout

    // ---- T -> N, final GEMM ----
    float* vN = qB;  // qB..(qB+8.39M) spans qB+kB, both dead
    trans_tn_k<<<1024, 256, 0, stream>>>(vp, vN);
    gemm_bias_k<false><<<gg, 256, 0, stream>>>(vN, outw, outb, (float*)d_out);
}

// Round 2
// 973.745 us; speedup vs baseline: 1.2593x; 1.2593x over previous
//
#include <hip/hip_runtime.h>
#include <cstddef>

#define PI2F 6.283185307179586f

// ============================ GEMM (M=16384, N=512, K=512) ============================
template<bool TOUT>
__global__ __launch_bounds__(256)
void gemm_bias_k(const float* __restrict__ X, const float* __restrict__ W,
                 const float* __restrict__ bias, float* __restrict__ out)
{
    __shared__ float As[16][68];
    __shared__ float Bs[16][68];
    __shared__ float Cs[64][68];
    const int tid = threadIdx.x;
    const int i = tid >> 4, j = tid & 15;
    const int m0 = blockIdx.x << 6, n0 = blockIdx.y << 6;
    const int lm = tid >> 2, lkq = tid & 3;
    const int lkk = tid >> 4, lnq = tid & 15;
    const float* Xp = X + (size_t)(m0 + lm) * 512 + lkq * 4;
    const float* Wp = W + (size_t)lkk * 512 + n0 + lnq * 4;
    float c[4][4] = {};
    for (int k0 = 0; k0 < 512; k0 += 16) {
        float4 a4 = *(const float4*)(Xp + k0);
        float4 b4 = *(const float4*)(Wp + (size_t)k0 * 512);
        As[lkq*4+0][lm] = a4.x;
        As[lkq*4+1][lm] = a4.y;
        As[lkq*4+2][lm] = a4.z;
        As[lkq*4+3][lm] = a4.w;
        *(float4*)&Bs[lkk][lnq*4] = b4;
        __syncthreads();
#pragma unroll
        for (int kk = 0; kk < 16; ++kk) {
            float4 av = *(const float4*)&As[kk][i*4];
            float4 bv = *(const float4*)&Bs[kk][j*4];
            float a[4] = {av.x, av.y, av.z, av.w};
            float b[4] = {bv.x, bv.y, bv.z, bv.w};
#pragma unroll
            for (int ii = 0; ii < 4; ++ii)
#pragma unroll
                for (int jj = 0; jj < 4; ++jj)
                    c[ii][jj] = fmaf(a[ii], b[jj], c[ii][jj]);
        }
        __syncthreads();
    }
    if constexpr (TOUT) {
        float bv[4];
#pragma unroll
        for (int r = 0; r < 4; ++r) bv[r] = bias[n0 + j*4 + r];
#pragma unroll
        for (int ii = 0; ii < 4; ++ii)
#pragma unroll
            for (int jj = 0; jj < 4; ++jj)
                Cs[j*4+jj][i*4+ii] = c[ii][jj] + bv[jj];
        __syncthreads();
        const int b_ = m0 >> 10, t0 = m0 & 1023;
        const int col = tid >> 2, seg = tid & 3;
        const int gc = n0 + col;
        const int h = gc & 7, e = gc >> 3;
        float* dst = out + (((size_t)(b_*8 + h) * 64 + e) << 10) + t0;
#pragma unroll
        for (int it = 0; it < 4; ++it) {
            int tl = (it*4 + seg) * 4;
            *(float4*)(dst + tl) = *(float4*)&Cs[col][tl];
        }
    } else {
#pragma unroll
        for (int ii = 0; ii < 4; ++ii) {
            float4 v;
            v.x = c[ii][0] + bias[n0 + j*4 + 0];
            v.y = c[ii][1] + bias[n0 + j*4 + 1];
            v.z = c[ii][2] + bias[n0 + j*4 + 2];
            v.w = c[ii][3] + bias[n0 + j*4 + 3];
            *(float4*)(out + (size_t)(m0 + i*4 + ii) * 512 + n0 + j*4) = v;
        }
    }
}

// ============================ fused wavelet + rfft-modes ============================
// block = (tensor, b, e); 256 threads. Input rows length 2L; outputs:
//   s-path rows (next-level input) to global, and QF/KF mode arrays for d and s paths.
// d path never touches global memory.
__global__ __launch_bounds__(256)
void wavelet_fft_k(const float* __restrict__ qin, const float* __restrict__ kin,
                   float* __restrict__ qs_out, float* __restrict__ ks_out,
                   float2* __restrict__ QFd, float2* __restrict__ KFd,
                   float2* __restrict__ QFs, float2* __restrict__ KFs,
                   const float* __restrict__ ecd, const float* __restrict__ ecs,
                   int L, int m)
{
    __shared__ float inb[8 * 512];       // input chunk: 8 rows x 2*CH (CH<=256)
    __shared__ float db[8 * 520];        // d path, stride L+1 (bank-conflict pad)
    __shared__ float sb[8 * 520];        // s path
    __shared__ float fd[128], fs[128];
    const int tid = threadIdx.x;
    const int tensor = blockIdx.x >> 10;
    const int b = (blockIdx.x >> 6) & 15;
    const int e = blockIdx.x & 63;
    const float* in = tensor ? kin : qin;
    float* souts = tensor ? ks_out : qs_out;
    if (tid < 128) fd[tid] = ecd[tid];
    else fs[tid - 128] = ecs[tid - 128];
    const int CH = L < 256 ? L : 256;
    const int LP = L + 1;
    const size_t rb = (size_t)(b * 8) * 64 + e;   // row index at h=0

    for (int t0 = 0; t0 < L; t0 += CH) {
        __syncthreads();
        int nv = (8 * 2 * CH) >> 2;     // float4 count
        for (int u = tid; u < nv; u += 256) {
            int h = (u * 4) / (2 * CH);
            int tt = (u * 4) % (2 * CH);
            *(float4*)&inb[h * (2 * CH) + tt] =
                *(const float4*)(in + (rb + (size_t)h * 64) * (size_t)(2 * L) + 2 * t0 + tt);
        }
        __syncthreads();
        for (int t = tid; t < CH; t += 256) {
            float xa[16];
#pragma unroll
            for (int h = 0; h < 8; ++h) {
                xa[h]     = inb[h * (2 * CH) + 2 * t];
                xa[8 + h] = inb[h * (2 * CH) + 2 * t + 1];
            }
#pragma unroll
            for (int jj = 0; jj < 8; ++jj) {
                float ad = 0.f, as_ = 0.f;
#pragma unroll
                for (int rr = 0; rr < 16; ++rr) {
                    ad  = fmaf(xa[rr], fd[rr * 8 + jj], ad);
                    as_ = fmaf(xa[rr], fs[rr * 8 + jj], as_);
                }
                db[jj * LP + t0 + t] = ad;
                sb[jj * LP + t0 + t] = as_;
                souts[(rb + (size_t)jj * 64) * (size_t)L + t0 + t] = as_;
            }
        }
    }
    __syncthreads();

    // fft phase: thread = (path p, row h, mode j)
    const int p = tid >> 7;
    const int h = (tid >> 4) & 7;
    const int j = tid & 15;
    if (j < m) {
        const float* src = (p ? sb : db) + h * LP;
        const float th = (PI2F / (float)L) * (float)j;
        float re = 0.f, im = 0.f;
        for (int t0 = 0; t0 < L; t0 += 128) {
            float c1, s1, cj, sj;
            sincosf(th, &s1, &c1);
            sincosf(th * (float)t0, &sj, &cj);
            int te = (t0 + 128 < L) ? t0 + 128 : L;
            for (int t = t0; t < te; ++t) {
                float x = src[t];
                re = fmaf(x, cj, re);
                im = fmaf(-x, sj, im);
                float cn = fmaf(cj, c1, -sj * s1);
                sj = fmaf(sj, c1, cj * s1);
                cj = cn;
            }
        }
        float2* dst = tensor ? (p ? KFs : KFd) : (p ? QFs : QFd);
        size_t row = rb + (size_t)h * 64;
        dst[row * m + j] = make_float2(re, im);
    }
}

// ============================ fused combine (tanh attention) + dual irfft ============================
// block = (bh = b*8+h, half); 256 threads. us = irfft(Ud_path), ud = irfft(Ud+Us paths).
__global__ __launch_bounds__(256)
void combine_irfft_k(const float2* __restrict__ QFd, const float2* __restrict__ KFd,
                     const float2* __restrict__ QFs, const float2* __restrict__ KFs,
                     float* __restrict__ us, float* __restrict__ ud,
                     int L, int m, float scale)
{
    __shared__ float2 Qs[2][64 * 16];
    __shared__ float2 Ks[2][64 * 16];
    __shared__ float2 Ss[2][16 * 16];
    __shared__ float2 Us[2][64 * 16];
    const int tid = threadIdx.x;
    const int half = blockIdx.x & 1;
    const int bh = blockIdx.x >> 1;
    const int tot = 64 * m;
    {
        const float4* g0 = (const float4*)(QFd + (size_t)bh * tot);
        const float4* g1 = (const float4*)(KFd + (size_t)bh * tot);
        const float4* g2 = (const float4*)(QFs + (size_t)bh * tot);
        const float4* g3 = (const float4*)(KFs + (size_t)bh * tot);
        int n4 = tot >> 1;   // float4 = 2 float2
        for (int u = tid; u < n4; u += 256) {
            ((float4*)Qs[0])[u] = g0[u];
            ((float4*)Ks[0])[u] = g1[u];
            ((float4*)Qs[1])[u] = g2[u];
            ((float4*)Ks[1])[u] = g3[u];
        }
        if (tot & 1) { // m==1: tot=64, odd float4 count handled scalar
            for (int u = tid; u < tot; u += 256) {
                Qs[0][u] = QFd[(size_t)bh * tot + u];
                Ks[0][u] = KFd[(size_t)bh * tot + u];
                Qs[1][u] = QFs[(size_t)bh * tot + u];
                Ks[1][u] = KFs[(size_t)bh * tot + u];
            }
        }
    }
    __syncthreads();
    // S = tanh(QF^T KF)  (complex), per path
    const int mm = m * m;
    for (int idx = tid; idx < 2 * mm; idx += 256) {
        int p = idx / mm;
        int r = idx - p * mm;
        int x = r / m, y = r - (r / m) * m;
        const float2* Qp = Qs[p];
        const float2* Kp = Ks[p];
        float sr = 0.f, si = 0.f;
        for (int ee = 0; ee < 64; ++ee) {
            float2 qq = Qp[ee * m + x], kk = Kp[ee * m + y];
            sr = fmaf(qq.x, kk.x, sr); sr = fmaf(-qq.y, kk.y, sr);
            si = fmaf(qq.x, kk.y, si); si = fmaf(qq.y, kk.x, si);
        }
        float twoa = fminf(fmaxf(2.f * sr, -30.f), 30.f);
        float e2 = expf(twoa);
        float inv = 1.f / e2;
        float s2b, c2b;
        sincosf(2.f * si, &s2b, &c2b);
        float den = 0.5f * (e2 + inv) + c2b;
        Ss[p][x * 16 + y] = make_float2(0.5f * (e2 - inv) / den, s2b / den);
    }
    __syncthreads();
    // U[p][e][x] = sum_y S[p][x][y] * KF[p][e][y]
    for (int idx = tid; idx < 2 * tot; idx += 256) {
        int p = idx / tot;
        int r = idx - p * tot;
        int ee = r / m, x = r - (r / m) * m;
        const float2* Kp = Ks[p];
        const float2* Sp = Ss[p];
        float ur = 0.f, ui = 0.f;
        for (int y = 0; y < m; ++y) {
            float2 tt = Sp[x * 16 + y], kk = Kp[ee * m + y];
            ur = fmaf(tt.x, kk.x, ur); ur = fmaf(-tt.y, kk.y, ur);
            ui = fmaf(tt.x, kk.y, ui); ui = fmaf(tt.y, kk.x, ui);
        }
        Us[p][ee * m + x] = make_float2(ur, ui);
    }
    __syncthreads();
    // Us[1] := Us[0] + Us[1]  (ud output modes)
    for (int idx = tid; idx < tot; idx += 256) {
        float2 a = Us[0][idx], bb = Us[1][idx];
        Us[1][idx] = make_float2(a.x + bb.x, a.y + bb.y);
    }
    __syncthreads();
    // dual irfft over this block's 32 e-rows
    const int eBase = half * 32;
    for (int u = tid; u < 32 * L; u += 256) {
        int ee = eBase + u / L;
        int t = u - (u / L) * L;
        const float2* Wd = Us[0] + ee * m;
        const float2* Wv = Us[1] + ee * m;
        float as_ = Wd[0].x;
        float ad_ = Wv[0].x;
        if (m > 1) {
            float s1, c1;
            __sincosf((PI2F / (float)L) * (float)t, &s1, &c1);
            float cj = c1, sj = s1;
            for (int jj = 1; jj < m; ++jj) {
                float2 dm = Wd[jj], vm = Wv[jj];
                as_ += 2.f * (dm.x * cj - dm.y * sj);
                ad_ += 2.f * (vm.x * cj - vm.y * sj);
                float cn = fmaf(cj, c1, -sj * s1);
                sj = fmaf(sj, c1, cj * s1);
                cj = cn;
            }
        }
        size_t row = (size_t)bh * 64 + ee;
        us[row * (size_t)L + t] = as_ * scale;
        ud[row * (size_t)L + t] = ad_ * scale;
    }
}

// ============================ reconstruction: v=(v+Us | Ud) -> even/odd ============================
__global__ __launch_bounds__(256)
void recon_k(const float* __restrict__ vprev, const float* __restrict__ uss,
             const float* __restrict__ udd, const float* __restrict__ rce,
             const float* __restrict__ rco, float* __restrict__ vout, int L)
{
    __shared__ float se[16][8];
    __shared__ float so[16][8];
    if (threadIdx.x < 128) se[threadIdx.x >> 3][threadIdx.x & 7] = rce[threadIdx.x];
    else { int u = threadIdx.x - 128; so[u >> 3][u & 7] = rco[u]; }
    __syncthreads();
    size_t idx = (size_t)blockIdx.x * 256 + threadIdx.x;
    if (idx >= (size_t)1024 * L) return;
    int t = (int)(idx % L);
    int e = (int)((idx / L) & 63);
    int b = (int)(idx / ((size_t)L * 64));
    float a[16];
#pragma unroll
    for (int h = 0; h < 8; ++h) {
        size_t p = ((size_t)(b*8 + h) * 64 + e) * L + t;
        a[h] = vprev[p] + uss[p];
        a[8+h] = udd[p];
    }
#pragma unroll
    for (int jj = 0; jj < 8; ++jj) {
        float ev = 0.f, od = 0.f;
#pragma unroll
        for (int rr = 0; rr < 16; ++rr) {
            ev = fmaf(a[rr], se[rr][jj], ev);
            od = fmaf(a[rr], so[rr][jj], od);
        }
        *(float2*)(vout + ((size_t)(b*8 + jj) * 64 + e) * (size_t)(2*L) + 2*t) = make_float2(ev, od);
    }
}

// ============================ transpose T[b][h][e][t] -> N[b][t][e*8+h] ============================
__global__ __launch_bounds__(256)
void trans_tn_k(const float* __restrict__ vT, float* __restrict__ vN)
{
    __shared__ float Ls[512][17];
    const int b = blockIdx.x >> 6;
    const int t0 = (blockIdx.x & 63) << 4;
    const int tid = threadIdx.x;
#pragma unroll
    for (int it = 0; it < 8; ++it) {
        int u = it * 256 + tid;
        int row = u >> 2, part = u & 3;
        float4 v = *(const float4*)(vT + ((size_t)b * 512 + row) * 1024 + t0 + part * 4);
        Ls[row][part*4+0] = v.x;
        Ls[row][part*4+1] = v.y;
        Ls[row][part*4+2] = v.z;
        Ls[row][part*4+3] = v.w;
    }
    __syncthreads();
#pragma unroll
    for (int it = 0; it < 8; ++it) {
        int u = it * 256 + tid;
        int cq = u & 127, tt = u >> 7;
        int c = cq * 4;
        float4 v;
        v.x = Ls[(((c+0) & 7) << 6) + ((c+0) >> 3)][tt];
        v.y = Ls[(((c+1) & 7) << 6) + ((c+1) >> 3)][tt];
        v.z = Ls[(((c+2) & 7) << 6) + ((c+2) >> 3)][tt];
        v.w = Ls[(((c+3) & 7) << 6) + ((c+3) >> 3)][tt];
        *(float4*)(vN + ((size_t)b * 1024 + t0 + tt) * 512 + c) = v;
    }
}

// ============================ driver ============================
extern "C" void kernel_launch(void* const* d_in, const int* in_sizes, int n_in,
                              void* d_out, int out_size, void* d_ws, size_t ws_size,
                              hipStream_t stream)
{
    const float* q    = (const float*)d_in[0];
    const float* k    = (const float*)d_in[1];
    const float* Lq_w = (const float*)d_in[3];
    const float* Lq_b = (const float*)d_in[4];
    const float* Lk_w = (const float*)d_in[5];
    const float* Lk_b = (const float*)d_in[6];
    const float* outw = (const float*)d_in[9];
    const float* outb = (const float*)d_in[10];
    const float* ec_s = (const float*)d_in[11];
    const float* ec_d = (const float*)d_in[12];
    const float* rc_e = (const float*)d_in[13];
    const float* rc_o = (const float*)d_in[14];

    float* ws = (float*)d_ws;
    float*  qA   = ws;                       // 8,388,608
    float*  kA   = qA + 8388608;             // 8,388,608
    float*  qB   = kA + 8388608;             // 4,194,304
    float*  kB   = qB + 4194304;             // 4,194,304
    float*  US   = kB + 4194304;             // 8,380,416
    float*  UD   = US + 8380416;             // 8,380,416
    float2* QFd  = (float2*)(UD + 8380416);  // 131,072 float2 each
    float2* KFd  = QFd + 131072;
    float2* QFs  = KFd + 131072;
    float2* KFs  = QFs + 131072;
    float*  zero2 = (float*)(KFs + 131072);  // 16,384 floats

    // ---- input projections (v path is dead code: FCA never reads v) ----
    dim3 gg(256, 8);
    gemm_bias_k<true><<<gg, 256, 0, stream>>>(q, Lq_w, Lq_b, qA);
    gemm_bias_k<true><<<gg, 256, 0, stream>>>(k, Lk_w, Lk_b, kA);
    hipMemsetAsync(zero2, 0, 16384 * sizeof(float), stream);

    size_t offs[9];
    { size_t o = 0; for (int l = 0; l < 9; ++l) { offs[l] = o; o += (size_t)8192 * (512 >> l); } }

    float* qcur = qA; float* kcur = kA;
    float* qnxt = qB; float* knxt = kB;
    for (int lvl = 0; lvl < 9; ++lvl) {
        int L = 512 >> lvl;
        int m = (L / 2 < 16) ? L / 2 : 16;
        wavelet_fft_k<<<2048, 256, 0, stream>>>(
            qcur, kcur, qnxt, knxt, QFd, KFd, QFs, KFs, ec_d, ec_s, L, m);
        combine_irfft_k<<<256, 256, 0, stream>>>(
            QFd, KFd, QFs, KFs, US + offs[lvl], UD + offs[lvl],
            L, m, 1.f / (4096.f * (float)L));
        float* t0 = qcur; qcur = qnxt; qnxt = t0;
        float* t1 = kcur; kcur = knxt; knxt = t1;
    }

    // ---- reconstruction (v starts as zeros; levels 9/10 contribute nothing) ----
    float* vp = zero2;
    float* bufs[2] = {qA, kA};
    int pb = 0;
    for (int i = 8; i >= 0; --i) {
        int L = 512 >> i;
        size_t thr = (size_t)1024 * L;
        float* vo = bufs[pb]; pb ^= 1;
        recon_k<<<(unsigned)((thr + 255) / 256), 256, 0, stream>>>(
            vp, US + offs[i], UD + offs[i], rc_e, rc_o, vo, L);
        vp = vo;
    }

    // ---- T -> N, final GEMM ----
    float* vN = qB;
    trans_tn_k<<<1024, 256, 0, stream>>>(vp, vN);
    gemm_bias_k<false><<<gg, 256, 0, stream>>>(vN, outw, outb, (float*)d_out);
}